// Round 10
// baseline (170.361 us; speedup 1.0000x reference)
//
#include <hip/hip_runtime.h>

// B=32, N=1024, D=256. out = softmax((x Wq^T + bq)(x Wk^T + bk)^T) (x Wv^T + bv)
// fp16 MFMA, fp32 accumulate.
// R15: proj's A-fragment loads were 1KB-stride scattered fp32 (16B used per 64B
// line = 4x HBM overfetch on traj, ~40us). New tconv kernel reads traj coalesced,
// repacks to fp16 fragment-major 'pt' (layout == pq's); proj A-loads become
// per-lane-contiguous 16B. pt aliases d_out (attn overwrites it last). attn =
// proven R11 62us version; proj W-pipeline unchanged (R11 staged).
#define NN 1024
#define DD 256

typedef __attribute__((ext_vector_type(8))) _Float16 f16x8;  // 8 fp16 = 4 VGPRs
typedef __attribute__((ext_vector_type(4))) _Float16 f16x4;  // 4 fp16 = 2 VGPRs
typedef __attribute__((ext_vector_type(4))) float f32x4;

union H8 { f16x8 v; _Float16 s[8]; };

__device__ __forceinline__ void g2lds16(const void* g, void* l) {
  __builtin_amdgcn_global_load_lds(
      (const __attribute__((address_space(1))) void*)g,
      (__attribute__((address_space(3))) void*)l, 16, 0, 0);
}

// ---------------- kernel 0: pack traj fp32 -> fp16 fragment-major --------------------
// pt[((g*8+kk)*64+l)*8+e] = traj[g*16 + (l&15)][kk*32 + (l>>4)*8 + e]
// Coalesced global read -> padded LDS -> fragment emit (coalesced write).
__global__ __launch_bounds__(256) void tconv_kernel(const float* __restrict__ traj,
                                                    _Float16* __restrict__ pt) {
  __shared__ float Ts[64 * 260];                 // 64 rows, stride 260 (pad 4) = 66.6 KB
  const int t = threadIdx.x;
  const int rb = blockIdx.x;                     // 512 blocks x 64 rows
  const float* src = traj + (size_t)rb * 64 * 256;
  // stage 64x256 fp32 coalesced; scatter into padded rows
#pragma unroll
  for (int i = 0; i < 16; ++i) {
    int flat = (i * 256 + t) * 4;                // linear f32 index
    int row = flat >> 8, d = flat & 255;
    *(float4*)&Ts[row * 260 + d] = ((const float4*)src)[i * 256 + t];
  }
  __syncthreads();
  // emit 2048 chunks of 8 fp16; chunk cc=((gl*8+kk)*64+l), thread does cc=t+i*256
  _Float16* dst = pt + (size_t)rb * 16384;
#pragma unroll
  for (int i = 0; i < 8; ++i) {
    int cc = i * 256 + t;
    int l = cc & 63, kk = (cc >> 6) & 7, gl = cc >> 9;
    int row = gl * 16 + (l & 15), d = kk * 32 + (l >> 4) * 8;
    const float* s8 = &Ts[row * 260 + d];
    H8 xx;
#pragma unroll
    for (int j = 0; j < 8; ++j) xx.s[j] = (_Float16)s8[j];
    *(f16x8*)(dst + (size_t)cc * 8) = xx.v;
  }
}

// ---------------- kernel 1: pack W fp32 -> fp16 fragment-major (32-col tiles) -------
__global__ void wconv_kernel(const float* __restrict__ Wq, const float* __restrict__ Wk,
                             const float* __restrict__ Wv, _Float16* __restrict__ pw) {
  int c = blockIdx.x * 256 + threadIdx.x;        // < 24576
  int lane = c & 63;
  int nt = (c >> 6) & 1;
  int kk = (c >> 7) & 7;
  int et = c >> 10;                              // 0..23
  int e = et * 32 + nt * 16 + (lane & 15);
  int d = kk * 32 + (lane >> 4) * 8;
  const float* W = (e < 256) ? Wq : (e < 512 ? Wk : Wv);
  const float* src = W + (e & 255) * 256 + d;
  H8 xx;
  for (int j = 0; j < 8; ++j) xx.s[j] = (_Float16)src[j];
  *(f16x8*)(pw + (size_t)c * 8) = xx.v;
}

// ---------------- kernel 2: QKV projection -------------------------------------------
// grid 512 = 256 m-tiles x 2 e-halves; 4 waves, wave owns 32 m-rows (2 A-sets).
// A-fragments from packed pt (coalesced per-lane 16B). W tiles dbuf'd via
// global_load_lds with counted vmcnt; epilogues wave-private.
__global__ __launch_bounds__(256, 2) void proj_kernel(
    const _Float16* __restrict__ pt,
    const float* __restrict__ bq, const float* __restrict__ bk, const float* __restrict__ bv,
    const _Float16* __restrict__ pw,
    _Float16* __restrict__ pq, _Float16* __restrict__ pk, _Float16* __restrict__ pv)
{
  __shared__ alignas(16) _Float16 Wl[2][8192];   // 2 x 16 KB W tiles
  __shared__ alignas(16) _Float16 Cs[4][1280];   // per-wave 32x40 staging (2.5 KB each)

  const int t = threadIdx.x;
  const int lane = t & 63, wave = t >> 6;
  const int col16 = lane & 15, quad = lane >> 4;
  const int mt = blockIdx.x >> 1, eh = blockIdx.x & 1;
  const int mbase = mt * 128;
  const int bb = mbase >> 10;

  // A fragments from pt: 2 sets of 16 rows; 8x16B coalesced loads per set
  f16x8 aq[2][8];
#pragma unroll
  for (int s = 0; s < 2; ++s) {
    int g = (mbase >> 4) + wave * 2 + s;
#pragma unroll
    for (int kk = 0; kk < 8; ++kk)
      aq[s][kk] = *(const f16x8*)(pt + (size_t)((g * 8 + kk) * 64 + lane) * 8);
  }

  const f32x4 zero = {0.f, 0.f, 0.f, 0.f};
  const int et0 = eh * 12;

  // prologue: stage W tiles 0 and 1 (4 g2lds16 per tile per thread)
  for (int i = 0; i < 4; ++i)
    g2lds16(pw + (size_t)et0 * 8192 + (size_t)(i * 256 + t) * 8, Wl[0] + (i * 256 + t) * 8);
  for (int i = 0; i < 4; ++i)
    g2lds16(pw + (size_t)(et0 + 1) * 8192 + (size_t)(i * 256 + t) * 8, Wl[1] + (i * 256 + t) * 8);

  for (int ei = 0; ei < 12; ++ei) {
    // counted wait: oldest outstanding = tile ei (aq's 16 loads are oldest and
    // retire with it). Steady state: tile ei+1 (4) + prev 2 stores in flight.
    if (ei == 0)      asm volatile("s_waitcnt vmcnt(4)" ::: "memory");
    else if (ei < 11) asm volatile("s_waitcnt vmcnt(6)" ::: "memory");
    else              asm volatile("s_waitcnt vmcnt(0)" ::: "memory");
    __builtin_amdgcn_s_barrier();      // tile ei landed for all waves
    asm volatile("" ::: "memory");

    const _Float16* wl = Wl[ei & 1];

    f32x4 acc[2][2];
    acc[0][0] = zero; acc[0][1] = zero; acc[1][0] = zero; acc[1][1] = zero;
    for (int kk = 0; kk < 8; ++kk)
      for (int nt = 0; nt < 2; ++nt) {
        f16x8 bw = *(const f16x8*)&wl[((kk * 2 + nt) * 64 + lane) * 8];
        acc[0][nt] = __builtin_amdgcn_mfma_f32_16x16x32_f16(aq[0][kk], bw, acc[0][nt], 0, 0, 0);
        acc[1][nt] = __builtin_amdgcn_mfma_f32_16x16x32_f16(aq[1][kk], bw, acc[1][nt], 0, 0, 0);
      }

    int e0 = eh * 384 + ei * 32;
    int sel = e0 >> 8;                 // 0=q 1=k 2=v
    const float* bias = (sel == 0) ? bq : (sel == 1 ? bk : bv);
    for (int nt = 0; nt < 2; ++nt) {
      float bvl = bias[(e0 & 255) + nt * 16 + col16];
      for (int s = 0; s < 2; ++s) {
        acc[s][nt][0] += bvl; acc[s][nt][1] += bvl;
        acc[s][nt][2] += bvl; acc[s][nt][3] += bvl;
      }
    }

    _Float16* cs = Cs[wave];           // wave-private: in-order DS pipe, no barriers
    if (sel < 2) {
      // C-layout staging: row = s*16+quad*4+r (stride 40), col = nt*16+col16
      for (int s = 0; s < 2; ++s)
        for (int nt = 0; nt < 2; ++nt)
          for (int r = 0; r < 4; ++r)
            cs[(s * 16 + quad * 4 + r) * 40 + nt * 16 + col16] = (_Float16)acc[s][nt][r];
      if (sel == 0) {
        for (int s = 0; s < 2; ++s) {
          f16x8 val = *(const f16x8*)&cs[(s * 16 + col16) * 40 + quad * 8];
          int g = (mbase >> 4) + wave * 2 + s;
          *(f16x8*)(pq + (size_t)((g * 8 + ei) * 64 + lane) * 8) = val;   // kk = ei (eh=0)
        }
      } else {
        int kkg = (e0 - 256) >> 5;
        for (int s = 0; s < 2; ++s) {
          f16x8 val = *(const f16x8*)&cs[(s * 16 + col16) * 40 + quad * 8];
          int kgg = ((mbase & 1023) >> 4) + wave * 2 + s;
          *(f16x8*)(pk + (size_t)(((bb * 64 + kgg) * 8 + kkg) * 64 + lane) * 8) = val;
        }
      }
    } else {
      // transposed staging: row = e_local = nt*16+col16 (stride 40), col = m 0..31
      for (int s = 0; s < 2; ++s)
        for (int nt = 0; nt < 2; ++nt)
          for (int r = 0; r < 4; ++r)
            cs[(nt * 16 + col16) * 40 + s * 16 + quad * 4 + r] = (_Float16)acc[s][nt][r];
      int kt32 = ((mbase & 1023) >> 5) + wave;   // wave's 32 rows = one 32-key group
      for (int dtl = 0; dtl < 2; ++dtl) {
        // key permutation pi baked in: slot j holds local key (j>>2)*16 + quad*4 + (j&3)
        // -> matches attn's swapped-QK P layout, so PV needs no shuffle/spill.
        const _Float16* base = &cs[(dtl * 16 + col16) * 40];
        H8 val;
        *(f16x4*)&val.s[0] = *(const f16x4*)&base[quad * 4];
        *(f16x4*)&val.s[4] = *(const f16x4*)&base[16 + quad * 4];
        int dtg = ((e0 - 512) >> 4) + dtl;
        *(f16x8*)(pv + (size_t)(((bb * 32 + kt32) * 16 + dtg) * 64 + lane) * 8) = val.v;
      }
    }

    asm volatile("" ::: "memory");
    __builtin_amdgcn_s_barrier();      // all waves done reading Wl[ei&1]
    if (ei < 10) {                     // issue tile ei+2 into the retired buffer
      const _Float16* ws = pw + (size_t)(et0 + ei + 2) * 8192;
      _Float16* wd = Wl[ei & 1];
      for (int i = 0; i < 4; ++i)
        g2lds16(ws + (size_t)(i * 256 + t) * 8, wd + (i * 256 + t) * 8);
    }
  }
}

// ---------------- kernel 3: flash attention (proven R11 structure) -------------------
// grid (32 b, 16 qt) x 256 thr; 4 waves x 16 q-rows. K,V both double-buffered
// (64 KB LDS, 2 blocks/CU). Depth-2 prefetch, counted vmcnt(8) + raw s_barrier.
// Swapped QK^T -> in-register softmax; pi-permuted pv; T13 defer-max THR=8.
__global__ __launch_bounds__(256, 2) void attn_kernel(
    const _Float16* __restrict__ pq, const _Float16* __restrict__ pk,
    const _Float16* __restrict__ pv, float* __restrict__ out)
{
  __shared__ alignas(16) _Float16 Ks[2][8192];   // 2 x 16 KB (32 keys x 256 d)
  __shared__ alignas(16) _Float16 Vs[2][8192];   // 2 x 16 KB

  const int t = threadIdx.x;
  const int lane = t & 63, wave = t >> 6;
  const int col16 = lane & 15, quad = lane >> 4;
  const int b = blockIdx.x, qt = blockIdx.y;     // bid%8 = b%8 -> per-batch XCD
  const int qrow0 = b * NN + qt * 64;

  // Q fragments from packed global (issued before staging: retired by first vmcnt(8))
  f16x8 aq[8];
  {
    int g = b * 64 + qt * 4 + wave;
#pragma unroll
    for (int kk = 0; kk < 8; ++kk)
      aq[kk] = *(const f16x8*)(pq + (size_t)((g * 8 + kk) * 64 + lane) * 8);
  }

  float m_i = -3.0e38f, l_i = 0.f;    // lane's q-row = col16
  f32x4 O[16];
  const f32x4 zero = {0.f, 0.f, 0.f, 0.f};
#pragma unroll
  for (int dt = 0; dt < 16; ++dt) O[dt] = zero;

  const _Float16* kbb = pk + (size_t)b * 64 * 8 * 64 * 8;
  const _Float16* vbb = pv + (size_t)b * 32 * 16 * 64 * 8;

  // prologue: stage tiles 0 and 1 (groups of 8 loads per tile: K then V)
#pragma unroll
  for (int i = 0; i < 4; ++i) g2lds16(kbb + (size_t)(i * 256 + t) * 8, &Ks[0][(i * 256 + t) * 8]);
#pragma unroll
  for (int i = 0; i < 4; ++i) g2lds16(vbb + (size_t)(i * 256 + t) * 8, &Vs[0][(i * 256 + t) * 8]);
#pragma unroll
  for (int i = 0; i < 4; ++i) g2lds16(kbb + 8192 + (size_t)(i * 256 + t) * 8, &Ks[1][(i * 256 + t) * 8]);
#pragma unroll
  for (int i = 0; i < 4; ++i) g2lds16(vbb + 8192 + (size_t)(i * 256 + t) * 8, &Vs[1][(i * 256 + t) * 8]);

  for (int kt = 0; kt < 32; ++kt) {
    // counted wait: oldest 8 outstanding = this iter's K,V tile; tile kt+1 stays in flight
    if (kt < 31) asm volatile("s_waitcnt vmcnt(8)" ::: "memory");
    else         asm volatile("s_waitcnt vmcnt(0)" ::: "memory");
    __builtin_amdgcn_s_barrier();      // A: everyone's tile-kt loads retired;
    asm volatile("" ::: "memory");     //    everyone's prev-iter LDS reads consumed

    // S' = K Q^T (swapped operands; A/B fragment layouts identical for this shape)
    const _Float16* ks = Ks[kt & 1];
    f32x4 S[2]; S[0] = zero; S[1] = zero;
    __builtin_amdgcn_s_setprio(1);
#pragma unroll
    for (int kk = 0; kk < 8; ++kk)
#pragma unroll
      for (int nt = 0; nt < 2; ++nt) {
        f16x8 bk_ = *(const f16x8*)&ks[((nt * 8 + kk) * 64 + lane) * 8];
        S[nt] = __builtin_amdgcn_mfma_f32_16x16x32_f16(bk_, aq[kk], S[nt], 0, 0, 0);
      }
    __builtin_amdgcn_s_setprio(0);

    // in-register softmax: lane holds S[q=col16][key = nt*16+quad*4+r]
    float sv[8];
#pragma unroll
    for (int nt = 0; nt < 2; ++nt)
#pragma unroll
      for (int r = 0; r < 4; ++r) sv[nt * 4 + r] = S[nt][r];
    float vmax = sv[0];
#pragma unroll
    for (int j = 1; j < 8; ++j) vmax = fmaxf(vmax, sv[j]);
    vmax = fmaxf(vmax, __shfl_xor(vmax, 16));
    vmax = fmaxf(vmax, __shfl_xor(vmax, 32));

    // T13 defer-max: rescale only when some row's max jumped by > 8
    if (__ballot(vmax > m_i + 8.0f)) {
      float nm = fmaxf(m_i, vmax);
      float alpha = __expf(m_i - nm);
      float a4[4];
#pragma unroll
      for (int r = 0; r < 4; ++r) a4[r] = __shfl(alpha, quad * 4 + r);
#pragma unroll
      for (int dt = 0; dt < 16; ++dt)
#pragma unroll
        for (int r = 0; r < 4; ++r) O[dt][r] *= a4[r];
      l_i *= alpha;
      m_i = nm;
    }
    float rs = 0.f;
    H8 px;
#pragma unroll
    for (int j = 0; j < 8; ++j) {
      float pj = __expf(sv[j] - m_i);  // bounded by e^8 = 2981 < fp16 max
      rs += pj;
      px.s[j] = (_Float16)pj;
    }
    rs += __shfl_xor(rs, 16);
    rs += __shfl_xor(rs, 32);
    l_i += rs;
    f16x8 ap = px.v;                   // PV A-operand straight from registers (pi-matched pv)

    // O += P V
    const _Float16* vs = Vs[kt & 1];
    __builtin_amdgcn_s_setprio(1);
#pragma unroll
    for (int dt = 0; dt < 16; ++dt) {
      f16x8 bv_ = *(const f16x8*)&vs[(dt * 64 + lane) * 8];
      O[dt] = __builtin_amdgcn_mfma_f32_16x16x32_f16(ap, bv_, O[dt], 0, 0, 0);
    }
    __builtin_amdgcn_s_setprio(0);

    asm volatile("" ::: "memory");
    __builtin_amdgcn_s_barrier();      // B: all waves done reading buffers [kt&1]
    if (kt < 30) {                     // depth-2: tile kt+2 -> buffers [kt&1]
      const _Float16* kg = kbb + (size_t)(kt + 2) * 8192;
      const _Float16* vg = vbb + (size_t)(kt + 2) * 8192;
      _Float16* kd = Ks[kt & 1];
      _Float16* vd = Vs[kt & 1];
#pragma unroll
      for (int i = 0; i < 4; ++i) g2lds16(kg + (size_t)(i * 256 + t) * 8, kd + (i * 256 + t) * 8);
#pragma unroll
      for (int i = 0; i < 4; ++i) g2lds16(vg + (size_t)(i * 256 + t) * 8, vd + (i * 256 + t) * 8);
    }
  }

  // epilogue: O /= l (broadcast l to C-layout), fp32 store
  float linv[4];
#pragma unroll
  for (int r = 0; r < 4; ++r) linv[r] = 1.0f / __shfl(l_i, quad * 4 + r);
#pragma unroll
  for (int r = 0; r < 4; ++r) {
    float* orow = out + (size_t)(qrow0 + wave * 16 + quad * 4 + r) * DD;
#pragma unroll
    for (int dt = 0; dt < 16; ++dt)
      orow[dt * 16 + col16] = O[dt][r] * linv[r];
  }
}

// ---------------- launch -------------------------------------------------------------
extern "C" void kernel_launch(void* const* d_in, const int* in_sizes, int n_in,
                              void* d_out, int out_size, void* d_ws, size_t ws_size,
                              hipStream_t stream) {
  const float* traj = (const float*)d_in[0];
  const float* Wq   = (const float*)d_in[1];
  const float* bq   = (const float*)d_in[2];
  const float* Wk   = (const float*)d_in[3];
  const float* bk   = (const float*)d_in[4];
  const float* Wv   = (const float*)d_in[5];
  const float* bv   = (const float*)d_in[6];

  // workspace (fp16): pq 16MB | pk 16MB | pv 16MB | pw 0.4MB
  // pt (packed traj, 16MB) aliases d_out: tconv writes it, proj reads it
  // (prologue only), attn overwrites d_out afterwards -- stream-ordered.
  _Float16* pq = (_Float16*)d_ws;
  _Float16* pk = pq + (size_t)32768 * 256;
  _Float16* pv = pk + (size_t)32768 * 256;
  _Float16* pw = pv + (size_t)32768 * 256;   // ~48.4 MB total
  _Float16* pt = (_Float16*)d_out;

  tconv_kernel<<<512, 256, 0, stream>>>(traj, pt);
  wconv_kernel<<<96, 256, 0, stream>>>(Wq, Wk, Wv, pw);
  proj_kernel<<<512, 256, 0, stream>>>(pt, bq, bk, bv, pw, pq, pk, pv);
  attn_kernel<<<dim3(32, 16), 256, 0, stream>>>(pq, pk, pv, (float*)d_out);
}

// Round 11
// 165.121 us; speedup vs baseline: 1.0317x; 1.0317x over previous
//
#include <hip/hip_runtime.h>

// B=32, N=1024, D=256. out = softmax((x Wq^T + bq)(x Wk^T + bk)^T) (x Wv^T + bv)
// fp16 MFMA, fp32 accumulate.
// R16: tconv dropped (R15: no overfetch existed; L3 absorbs the eh-duplicate traj
// read). proj: per-ei bias GLOBAL loads were the youngest VMEM op each iteration
// -> compiler's use-wait drained vmcnt to 0, defeating the counted-vmcnt W
// pipeline every ei. Bias now staged to LDS once (Bs[768], +3KB); in-loop bias
// reads are DS-pipe only. Everything else byte-identical to R13 (163.8us best):
// attn = proven 62us R11 structure; wconv unchanged.
#define NN 1024
#define DD 256

typedef __attribute__((ext_vector_type(8))) _Float16 f16x8;  // 8 fp16 = 4 VGPRs
typedef __attribute__((ext_vector_type(4))) _Float16 f16x4;  // 4 fp16 = 2 VGPRs
typedef __attribute__((ext_vector_type(4))) float f32x4;

union H8 { f16x8 v; _Float16 s[8]; };

__device__ __forceinline__ void g2lds16(const void* g, void* l) {
  __builtin_amdgcn_global_load_lds(
      (const __attribute__((address_space(1))) void*)g,
      (__attribute__((address_space(3))) void*)l, 16, 0, 0);
}

// ---------------- kernel 1: pack W fp32 -> fp16 fragment-major (32-col tiles) -------
// chunk c = ((et*8+kk)*2+nt)*64+lane ; data = W[e=et*32+nt*16+c16][d=kk*32+qd*8..+7]
__global__ void wconv_kernel(const float* __restrict__ Wq, const float* __restrict__ Wk,
                             const float* __restrict__ Wv, _Float16* __restrict__ pw) {
  int c = blockIdx.x * 256 + threadIdx.x;        // < 24576
  int lane = c & 63;
  int nt = (c >> 6) & 1;
  int kk = (c >> 7) & 7;
  int et = c >> 10;                              // 0..23
  int e = et * 32 + nt * 16 + (lane & 15);
  int d = kk * 32 + (lane >> 4) * 8;
  const float* W = (e < 256) ? Wq : (e < 512 ? Wk : Wv);
  const float* src = W + (e & 255) * 256 + d;
  H8 xx;
  for (int j = 0; j < 8; ++j) xx.s[j] = (_Float16)src[j];
  *(f16x8*)(pw + (size_t)c * 8) = xx.v;
}

// ---------------- kernel 2: QKV projection -------------------------------------------
// grid 512 = 256 m-tiles x 2 e-halves; 4 waves, wave owns 32 m-rows (2 A-sets).
// 32-col W tiles dbuf'd via global_load_lds with counted vmcnt; bias in LDS so the
// loop's only VMEM = 2 stores + prefetch (counted scheme intact); epilogues
// wave-private.
__global__ __launch_bounds__(256, 2) void proj_kernel(
    const float* __restrict__ traj,
    const float* __restrict__ bq, const float* __restrict__ bk, const float* __restrict__ bv,
    const _Float16* __restrict__ pw,
    _Float16* __restrict__ pq, _Float16* __restrict__ pk, _Float16* __restrict__ pv)
{
  __shared__ alignas(16) _Float16 Wl[2][8192];   // 2 x 16 KB W tiles
  __shared__ alignas(16) _Float16 Cs[4][1280];   // per-wave 32x40 staging (2.5 KB each)
  __shared__ float Bs[768];                      // bq | bk | bv staged once (3 KB)

  const int t = threadIdx.x;
  const int lane = t & 63, wave = t >> 6;
  const int col16 = lane & 15, quad = lane >> 4;
  const int mt = blockIdx.x >> 1, eh = blockIdx.x & 1;
  const int mbase = mt * 128;
  const int bb = mbase >> 10;

  // bias -> registers -> LDS (oldest VMEM ops; retired before first ds_write)
  float btmp[3];
#pragma unroll
  for (int i = 0; i < 3; ++i) {
    int idx = i * 256 + t;
    const float* bsrc = (idx < 256) ? (bq + idx) : (idx < 512 ? (bk + idx - 256) : (bv + idx - 512));
    btmp[i] = *bsrc;
  }

  // A fragments, 2 sets of 16 rows (rows mbase + wave*32 + s*16 + col16)
  f16x8 aq[2][8];
  for (int s = 0; s < 2; ++s) {
    const float* ap = traj + (size_t)(mbase + wave * 32 + s * 16 + col16) * DD;
    for (int kk = 0; kk < 8; ++kk) {
      float4 u0 = *(const float4*)(ap + kk * 32 + quad * 8);
      float4 u1 = *(const float4*)(ap + kk * 32 + quad * 8 + 4);
      H8 xx;
      xx.s[0] = (_Float16)u0.x; xx.s[1] = (_Float16)u0.y;
      xx.s[2] = (_Float16)u0.z; xx.s[3] = (_Float16)u0.w;
      xx.s[4] = (_Float16)u1.x; xx.s[5] = (_Float16)u1.y;
      xx.s[6] = (_Float16)u1.z; xx.s[7] = (_Float16)u1.w;
      aq[s][kk] = xx.v;
    }
  }

  const f32x4 zero = {0.f, 0.f, 0.f, 0.f};
  const int et0 = eh * 12;

  // prologue: stage W tiles 0 and 1 (4 g2lds16 per tile per thread)
  for (int i = 0; i < 4; ++i)
    g2lds16(pw + (size_t)et0 * 8192 + (size_t)(i * 256 + t) * 8, Wl[0] + (i * 256 + t) * 8);
  for (int i = 0; i < 4; ++i)
    g2lds16(pw + (size_t)(et0 + 1) * 8192 + (size_t)(i * 256 + t) * 8, Wl[1] + (i * 256 + t) * 8);

  // commit bias to LDS (forces wait on bias loads only -- they're oldest)
#pragma unroll
  for (int i = 0; i < 3; ++i) Bs[i * 256 + t] = btmp[i];

  for (int ei = 0; ei < 12; ++ei) {
    // counted wait: oldest outstanding = A-loads + tile ei. Steady state: tile
    // ei+1 (4) + prev epilogue's 2 global stores stay in flight -> vmcnt(6).
    if (ei == 0)      asm volatile("s_waitcnt vmcnt(4)" ::: "memory");
    else if (ei < 11) asm volatile("s_waitcnt vmcnt(6)" ::: "memory");
    else              asm volatile("s_waitcnt vmcnt(0)" ::: "memory");
    __builtin_amdgcn_s_barrier();      // tile ei landed for all waves; Bs visible
    asm volatile("" ::: "memory");

    const _Float16* wl = Wl[ei & 1];

    f32x4 acc[2][2];
    acc[0][0] = zero; acc[0][1] = zero; acc[1][0] = zero; acc[1][1] = zero;
    for (int kk = 0; kk < 8; ++kk)
      for (int nt = 0; nt < 2; ++nt) {
        f16x8 bw = *(const f16x8*)&wl[((kk * 2 + nt) * 64 + lane) * 8];
        acc[0][nt] = __builtin_amdgcn_mfma_f32_16x16x32_f16(aq[0][kk], bw, acc[0][nt], 0, 0, 0);
        acc[1][nt] = __builtin_amdgcn_mfma_f32_16x16x32_f16(aq[1][kk], bw, acc[1][nt], 0, 0, 0);
      }

    int e0 = eh * 384 + ei * 32;
    int sel = e0 >> 8;                 // 0=q 1=k 2=v
    for (int nt = 0; nt < 2; ++nt) {
      float bvl = Bs[e0 + nt * 16 + col16];   // DS pipe: no vmcnt interaction
      for (int s = 0; s < 2; ++s) {
        acc[s][nt][0] += bvl; acc[s][nt][1] += bvl;
        acc[s][nt][2] += bvl; acc[s][nt][3] += bvl;
      }
    }

    _Float16* cs = Cs[wave];           // wave-private: in-order DS pipe, no barriers
    if (sel < 2) {
      // C-layout staging: row = s*16+quad*4+r (stride 40), col = nt*16+col16
      for (int s = 0; s < 2; ++s)
        for (int nt = 0; nt < 2; ++nt)
          for (int r = 0; r < 4; ++r)
            cs[(s * 16 + quad * 4 + r) * 40 + nt * 16 + col16] = (_Float16)acc[s][nt][r];
      if (sel == 0) {
        for (int s = 0; s < 2; ++s) {
          f16x8 val = *(const f16x8*)&cs[(s * 16 + col16) * 40 + quad * 8];
          int g = (mbase >> 4) + wave * 2 + s;
          *(f16x8*)(pq + (size_t)((g * 8 + ei) * 64 + lane) * 8) = val;   // kk = ei (eh=0)
        }
      } else {
        int kkg = (e0 - 256) >> 5;
        for (int s = 0; s < 2; ++s) {
          f16x8 val = *(const f16x8*)&cs[(s * 16 + col16) * 40 + quad * 8];
          int kgg = ((mbase & 1023) >> 4) + wave * 2 + s;
          *(f16x8*)(pk + (size_t)(((bb * 64 + kgg) * 8 + kkg) * 64 + lane) * 8) = val;
        }
      }
    } else {
      // transposed staging: row = e_local = nt*16+col16 (stride 40), col = m 0..31
      for (int s = 0; s < 2; ++s)
        for (int nt = 0; nt < 2; ++nt)
          for (int r = 0; r < 4; ++r)
            cs[(nt * 16 + col16) * 40 + s * 16 + quad * 4 + r] = (_Float16)acc[s][nt][r];
      int kt32 = ((mbase & 1023) >> 5) + wave;   // wave's 32 rows = one 32-key group
      for (int dtl = 0; dtl < 2; ++dtl) {
        // key permutation pi baked in: slot j holds local key (j>>2)*16 + quad*4 + (j&3)
        // -> matches attn's swapped-QK P layout, so PV needs no shuffle/spill.
        const _Float16* base = &cs[(dtl * 16 + col16) * 40];
        H8 val;
        *(f16x4*)&val.s[0] = *(const f16x4*)&base[quad * 4];
        *(f16x4*)&val.s[4] = *(const f16x4*)&base[16 + quad * 4];
        int dtg = ((e0 - 512) >> 4) + dtl;
        *(f16x8*)(pv + (size_t)(((bb * 32 + kt32) * 16 + dtg) * 64 + lane) * 8) = val.v;
      }
    }

    asm volatile("" ::: "memory");
    __builtin_amdgcn_s_barrier();      // all waves done reading Wl[ei&1]
    if (ei < 10) {                     // issue tile ei+2 into the retired buffer
      const _Float16* ws = pw + (size_t)(et0 + ei + 2) * 8192;
      _Float16* wd = Wl[ei & 1];
      for (int i = 0; i < 4; ++i)
        g2lds16(ws + (size_t)(i * 256 + t) * 8, wd + (i * 256 + t) * 8);
    }
  }
}

// ---------------- kernel 3: flash attention (proven R11 structure) -------------------
// grid (32 b, 16 qt) x 256 thr; 4 waves x 16 q-rows. K,V both double-buffered
// (64 KB LDS, 2 blocks/CU). Depth-2 prefetch, counted vmcnt(8) + raw s_barrier.
// Swapped QK^T -> in-register softmax; pi-permuted pv; T13 defer-max THR=8.
__global__ __launch_bounds__(256, 2) void attn_kernel(
    const _Float16* __restrict__ pq, const _Float16* __restrict__ pk,
    const _Float16* __restrict__ pv, float* __restrict__ out)
{
  __shared__ alignas(16) _Float16 Ks[2][8192];   // 2 x 16 KB (32 keys x 256 d)
  __shared__ alignas(16) _Float16 Vs[2][8192];   // 2 x 16 KB

  const int t = threadIdx.x;
  const int lane = t & 63, wave = t >> 6;
  const int col16 = lane & 15, quad = lane >> 4;
  const int b = blockIdx.x, qt = blockIdx.y;     // bid%8 = b%8 -> per-batch XCD
  const int qrow0 = b * NN + qt * 64;

  // Q fragments from packed global (issued before staging: retired by first vmcnt(8))
  f16x8 aq[8];
  {
    int g = b * 64 + qt * 4 + wave;
#pragma unroll
    for (int kk = 0; kk < 8; ++kk)
      aq[kk] = *(const f16x8*)(pq + (size_t)((g * 8 + kk) * 64 + lane) * 8);
  }

  float m_i = -3.0e38f, l_i = 0.f;    // lane's q-row = col16
  f32x4 O[16];
  const f32x4 zero = {0.f, 0.f, 0.f, 0.f};
#pragma unroll
  for (int dt = 0; dt < 16; ++dt) O[dt] = zero;

  const _Float16* kbb = pk + (size_t)b * 64 * 8 * 64 * 8;
  const _Float16* vbb = pv + (size_t)b * 32 * 16 * 64 * 8;

  // prologue: stage tiles 0 and 1 (groups of 8 loads per tile: K then V)
#pragma unroll
  for (int i = 0; i < 4; ++i) g2lds16(kbb + (size_t)(i * 256 + t) * 8, &Ks[0][(i * 256 + t) * 8]);
#pragma unroll
  for (int i = 0; i < 4; ++i) g2lds16(vbb + (size_t)(i * 256 + t) * 8, &Vs[0][(i * 256 + t) * 8]);
#pragma unroll
  for (int i = 0; i < 4; ++i) g2lds16(kbb + 8192 + (size_t)(i * 256 + t) * 8, &Ks[1][(i * 256 + t) * 8]);
#pragma unroll
  for (int i = 0; i < 4; ++i) g2lds16(vbb + 8192 + (size_t)(i * 256 + t) * 8, &Vs[1][(i * 256 + t) * 8]);

  for (int kt = 0; kt < 32; ++kt) {
    // counted wait: oldest 8 outstanding = this iter's K,V tile; tile kt+1 stays in flight
    if (kt < 31) asm volatile("s_waitcnt vmcnt(8)" ::: "memory");
    else         asm volatile("s_waitcnt vmcnt(0)" ::: "memory");
    __builtin_amdgcn_s_barrier();      // A: everyone's tile-kt loads retired;
    asm volatile("" ::: "memory");     //    everyone's prev-iter LDS reads consumed

    // S' = K Q^T (swapped operands; A/B fragment layouts identical for this shape)
    const _Float16* ks = Ks[kt & 1];
    f32x4 S[2]; S[0] = zero; S[1] = zero;
    __builtin_amdgcn_s_setprio(1);
#pragma unroll
    for (int kk = 0; kk < 8; ++kk)
#pragma unroll
      for (int nt = 0; nt < 2; ++nt) {
        f16x8 bk_ = *(const f16x8*)&ks[((nt * 8 + kk) * 64 + lane) * 8];
        S[nt] = __builtin_amdgcn_mfma_f32_16x16x32_f16(bk_, aq[kk], S[nt], 0, 0, 0);
      }
    __builtin_amdgcn_s_setprio(0);

    // in-register softmax: lane holds S[q=col16][key = nt*16+quad*4+r]
    float sv[8];
#pragma unroll
    for (int nt = 0; nt < 2; ++nt)
#pragma unroll
      for (int r = 0; r < 4; ++r) sv[nt * 4 + r] = S[nt][r];
    float vmax = sv[0];
#pragma unroll
    for (int j = 1; j < 8; ++j) vmax = fmaxf(vmax, sv[j]);
    vmax = fmaxf(vmax, __shfl_xor(vmax, 16));
    vmax = fmaxf(vmax, __shfl_xor(vmax, 32));

    // T13 defer-max: rescale only when some row's max jumped by > 8
    if (__ballot(vmax > m_i + 8.0f)) {
      float nm = fmaxf(m_i, vmax);
      float alpha = __expf(m_i - nm);
      float a4[4];
#pragma unroll
      for (int r = 0; r < 4; ++r) a4[r] = __shfl(alpha, quad * 4 + r);
#pragma unroll
      for (int dt = 0; dt < 16; ++dt)
#pragma unroll
        for (int r = 0; r < 4; ++r) O[dt][r] *= a4[r];
      l_i *= alpha;
      m_i = nm;
    }
    float rs = 0.f;
    H8 px;
#pragma unroll
    for (int j = 0; j < 8; ++j) {
      float pj = __expf(sv[j] - m_i);  // bounded by e^8 = 2981 < fp16 max
      rs += pj;
      px.s[j] = (_Float16)pj;
    }
    rs += __shfl_xor(rs, 16);
    rs += __shfl_xor(rs, 32);
    l_i += rs;
    f16x8 ap = px.v;                   // PV A-operand straight from registers (pi-matched pv)

    // O += P V
    const _Float16* vs = Vs[kt & 1];
    __builtin_amdgcn_s_setprio(1);
#pragma unroll
    for (int dt = 0; dt < 16; ++dt) {
      f16x8 bv_ = *(const f16x8*)&vs[(dt * 64 + lane) * 8];
      O[dt] = __builtin_amdgcn_mfma_f32_16x16x32_f16(ap, bv_, O[dt], 0, 0, 0);
    }
    __builtin_amdgcn_s_setprio(0);

    asm volatile("" ::: "memory");
    __builtin_amdgcn_s_barrier();      // B: all waves done reading buffers [kt&1]
    if (kt < 30) {                     // depth-2: tile kt+2 -> buffers [kt&1]
      const _Float16* kg = kbb + (size_t)(kt + 2) * 8192;
      const _Float16* vg = vbb + (size_t)(kt + 2) * 8192;
      _Float16* kd = Ks[kt & 1];
      _Float16* vd = Vs[kt & 1];
#pragma unroll
      for (int i = 0; i < 4; ++i) g2lds16(kg + (size_t)(i * 256 + t) * 8, kd + (i * 256 + t) * 8);
#pragma unroll
      for (int i = 0; i < 4; ++i) g2lds16(vg + (size_t)(i * 256 + t) * 8, vd + (i * 256 + t) * 8);
    }
  }

  // epilogue: O /= l (broadcast l to C-layout), fp32 store
  float linv[4];
#pragma unroll
  for (int r = 0; r < 4; ++r) linv[r] = 1.0f / __shfl(l_i, quad * 4 + r);
#pragma unroll
  for (int r = 0; r < 4; ++r) {
    float* orow = out + (size_t)(qrow0 + wave * 16 + quad * 4 + r) * DD;
#pragma unroll
    for (int dt = 0; dt < 16; ++dt)
      orow[dt * 16 + col16] = O[dt][r] * linv[r];
  }
}

// ---------------- launch -------------------------------------------------------------
extern "C" void kernel_launch(void* const* d_in, const int* in_sizes, int n_in,
                              void* d_out, int out_size, void* d_ws, size_t ws_size,
                              hipStream_t stream) {
  const float* traj = (const float*)d_in[0];
  const float* Wq   = (const float*)d_in[1];
  const float* bq   = (const float*)d_in[2];
  const float* Wk   = (const float*)d_in[3];
  const float* bk   = (const float*)d_in[4];
  const float* Wv   = (const float*)d_in[5];
  const float* bv   = (const float*)d_in[6];

  // workspace (fp16): pq 16MB | pk 16MB | pv 16MB | pw 0.4MB  (all packed fragment-major)
  _Float16* pq = (_Float16*)d_ws;
  _Float16* pk = pq + (size_t)32768 * 256;
  _Float16* pv = pk + (size_t)32768 * 256;
  _Float16* pw = pv + (size_t)32768 * 256;   // ~48.4 MB total

  wconv_kernel<<<96, 256, 0, stream>>>(Wq, Wk, Wv, pw);
  proj_kernel<<<512, 256, 0, stream>>>(traj, bq, bk, bv, pw, pq, pk, pv);
  attn_kernel<<<dim3(32, 16), 256, 0, stream>>>(pq, pk, pv, (float*)d_out);
}